// Round 8
// baseline (2285.077 us; speedup 1.0000x reference)
//
#include <hip/hip_runtime.h>
#include <cstdint>
#include <cstddef>

#define NTOK  2048
#define HIDN  2048
#define IM    768
#define NE    32
#define TOPK  8
#define NGRP  8
#define GSZ   4
#define TKG   4

typedef __attribute__((ext_vector_type(8))) short bf16x8_t;
typedef __attribute__((ext_vector_type(4))) float f32x4_t;

__device__ __forceinline__ unsigned short f2bf(float f) {
    union { float f; unsigned u; } v; v.f = f;
    unsigned r = v.u + 0x7FFFu + ((v.u >> 16) & 1u);
    return (unsigned short)(r >> 16);
}

// ---------------------------------------------------------------- router
// f64 logits (fixed-order reduce) -> f32 scores -> selection with an
// eps-band preferring the HIGHER index (measured: the one knife-edge token,
// margin ~1e-8..1e-7, resolves to the higher index in the np reference's
// f32 arithmetic; all other margins >= 1e-3 so the band is inert elsewhere).
__global__ __launch_bounds__(256) void router_kernel(
    const float* __restrict__ x, const float* __restrict__ rw,
    const float* __restrict__ bias, unsigned short* __restrict__ x_bf,
    int* __restrict__ counts, int* __restrict__ tok_list, float* __restrict__ w_list)
{
    __shared__ float xs[HIDN];
    __shared__ double part[256];
    __shared__ double lg[NE];
    const int t = blockIdx.x, tid = threadIdx.x;

#pragma unroll
    for (int p = 0; p < 2; ++p) {
        int i = (p * 256 + tid) * 4;
        float4 v = *reinterpret_cast<const float4*>(x + (size_t)t * HIDN + i);
        *reinterpret_cast<float4*>(&xs[i]) = v;
        ushort4 b;
        b.x = f2bf(v.x); b.y = f2bf(v.y); b.z = f2bf(v.z); b.w = f2bf(v.w);
        *reinterpret_cast<ushort4*>(x_bf + (size_t)t * HIDN + i) = b;
    }
    __syncthreads();
    {
        int e = tid >> 3, l8 = tid & 7;
        const float* wrow = rw + (size_t)e * HIDN;
        double acc = 0.0;
        for (int k = l8 * 4; k < HIDN; k += 32) {
            float4 v = *reinterpret_cast<const float4*>(wrow + k);
            acc += (double)v.x * (double)xs[k]     + (double)v.y * (double)xs[k + 1]
                 + (double)v.z * (double)xs[k + 2] + (double)v.w * (double)xs[k + 3];
        }
        part[tid] = acc;
    }
    __syncthreads();
    if ((tid & 7) == 0) {
        int e = tid >> 3;
        double s = 0.0;
        for (int i = 0; i < 8; ++i) s += part[e * 8 + i];
        lg[e] = s;
    }
    __syncthreads();
    if (tid == 0) {
        const float EPS = 3e-7f;
        float s32[NE], sfc[NE], gs[NGRP];
        for (int e = 0; e < NE; ++e) {
            s32[e] = (float)(1.0 / (1.0 + exp(-lg[e])));   // f32-quantized score
            sfc[e] = s32[e] + bias[e];
        }
        for (int g = 0; g < NGRP; ++g) {
            float m1 = -1e30f, m2 = -1e30f;
            for (int i = 0; i < GSZ; ++i) {
                float v = sfc[g * GSZ + i];
                if (v > m1) { m2 = m1; m1 = v; }
                else if (v > m2) m2 = v;
            }
            gs[g] = m1 + m2;
        }
        // group top-4: within-EPS band -> highest index
        unsigned gmask = 0;
        for (int it = 0; it < TKG; ++it) {
            float best = -1e30f;
            for (int g = 0; g < NGRP; ++g)
                if (!((gmask >> g) & 1u) && gs[g] > best) best = gs[g];
            int bg = 0;
            for (int g = 0; g < NGRP; ++g)
                if (!((gmask >> g) & 1u) && gs[g] >= best - EPS) bg = g;
            gmask |= 1u << bg;
        }
        // expert top-8 within selected groups: within-EPS band -> highest index
        unsigned emask = 0;
        int idxs[TOPK]; float wv[TOPK];
        float wsum = 0.f;
        for (int j = 0; j < TOPK; ++j) {
            float best = -1e30f;
            for (int e = 0; e < NE; ++e)
                if (((gmask >> (e >> 2)) & 1u) && !((emask >> e) & 1u) && sfc[e] > best)
                    best = sfc[e];
            int be = 0;
            for (int e = 0; e < NE; ++e)
                if (((gmask >> (e >> 2)) & 1u) && !((emask >> e) & 1u) && sfc[e] >= best - EPS)
                    be = e;
            emask |= 1u << be;
            idxs[j] = be;
            wv[j] = s32[be];
            wsum += s32[be];
        }
        float den = wsum + 1e-20f;
        for (int j = 0; j < TOPK; ++j) {
            int e = idxs[j];
            int pos = atomicAdd(&counts[e], 1);
            tok_list[e * NTOK + pos] = t;
            w_list[e * NTOK + pos] = (wv[j] / den) * 2.5f;
        }
    }
}

__global__ void zero_counts_kernel(int* __restrict__ counts) {
    if (threadIdx.x < NE && blockIdx.x == 0) counts[threadIdx.x] = 0;
}

__global__ void prefix_kernel(const int* __restrict__ counts, int* __restrict__ offsets) {
    if (threadIdx.x == 0 && blockIdx.x == 0) {
        int a = 0;
        for (int e = 0; e < NE; ++e) { offsets[e] = a; a += counts[e]; }
    }
}

// ---------------------------------------------------------------- gate_up (+SiLU fused)
template<bool SHARED>
__global__ __launch_bounds__(256) void gateup_kernel(
    const unsigned short* __restrict__ x_bf,
    const float* __restrict__ gup,
    const float* __restrict__ sgw, const float* __restrict__ suw,
    const int* __restrict__ counts, const int* __restrict__ offsets,
    const int* __restrict__ tok_list,
    unsigned short* __restrict__ h_out)
{
    const int NIT = IM / 64;
    const int NTT = NTOK / 128;
    int bid = blockIdx.x;
    int e, it, tt;
    if (SHARED) { e = 0; it = bid / NTT; tt = bid % NTT; }
    else { e = bid / (NIT * NTT); int r = bid % (NIT * NTT); it = r / NTT; tt = r % NTT; }
    const int cnt = SHARED ? NTOK : counts[e];
    const int ts = tt * 128;
    if (ts >= cnt) return;
    const int base = SHARED ? 0 : offsets[e];
    const float* Bg = SHARED ? (sgw + (size_t)it * 64 * HIDN)
                             : (gup + (size_t)e * (2 * IM) * HIDN + (size_t)it * 64 * HIDN);
    const float* Bu = SHARED ? (suw + (size_t)it * 64 * HIDN)
                             : (gup + (size_t)e * (2 * IM) * HIDN + (size_t)(IM + it * 64) * HIDN);

    __shared__ unsigned short As[128][32];
    __shared__ unsigned short Bs[128][32];

    const int tid = threadIdx.x;
    const int lane = tid & 63, wid = tid >> 6;
    const int wr = wid >> 1, wc = wid & 1;

    size_t arow[2];
#pragma unroll
    for (int p = 0; p < 2; ++p) {
        int r = p * 64 + (tid >> 2);
        int gi = ts + r;
        int tok;
        if (SHARED) tok = (gi < NTOK) ? gi : 0;
        else        tok = (gi < cnt) ? tok_list[e * NTOK + gi] : 0;
        arow[p] = (size_t)tok * HIDN + (size_t)((tid & 3) * 8);
    }

    f32x4_t accg[4][2] = {};
    f32x4_t accu[4][2] = {};

    for (int k0 = 0; k0 < HIDN; k0 += 32) {
        uint4 av[2];
#pragma unroll
        for (int p = 0; p < 2; ++p)
            av[p] = *reinterpret_cast<const uint4*>(x_bf + arow[p] + k0);
        ushort4 bv[4];
#pragma unroll
        for (int q = 0; q < 4; ++q) {
            int rr = q * 32 + (tid >> 3);
            const float* src = (q < 2) ? (Bg + (size_t)rr * HIDN)
                                       : (Bu + (size_t)(rr - 64) * HIDN);
            float4 f = *reinterpret_cast<const float4*>(src + k0 + (tid & 7) * 4);
            ushort4 b;
            b.x = f2bf(f.x); b.y = f2bf(f.y); b.z = f2bf(f.z); b.w = f2bf(f.w);
            bv[q] = b;
        }
        __syncthreads();
#pragma unroll
        for (int p = 0; p < 2; ++p)
            *reinterpret_cast<uint4*>(&As[p * 64 + (tid >> 2)][(tid & 3) * 8]) = av[p];
#pragma unroll
        for (int q = 0; q < 4; ++q)
            *reinterpret_cast<ushort4*>(&Bs[q * 32 + (tid >> 3)][(tid & 7) * 4]) = bv[q];
        __syncthreads();

        bf16x8_t a[4], bgf[2], buf_[2];
#pragma unroll
        for (int m = 0; m < 4; ++m)
            a[m] = *reinterpret_cast<const bf16x8_t*>(&As[wr * 64 + m * 16 + (lane & 15)][(lane >> 4) * 8]);
#pragma unroll
        for (int n = 0; n < 2; ++n) {
            bgf[n]  = *reinterpret_cast<const bf16x8_t*>(&Bs[wc * 32 + n * 16 + (lane & 15)][(lane >> 4) * 8]);
            buf_[n] = *reinterpret_cast<const bf16x8_t*>(&Bs[64 + wc * 32 + n * 16 + (lane & 15)][(lane >> 4) * 8]);
        }
#pragma unroll
        for (int m = 0; m < 4; ++m)
#pragma unroll
            for (int n = 0; n < 2; ++n) {
                accg[m][n] = __builtin_amdgcn_mfma_f32_16x16x32_bf16(a[m], bgf[n],  accg[m][n], 0, 0, 0);
                accu[m][n] = __builtin_amdgcn_mfma_f32_16x16x32_bf16(a[m], buf_[n], accu[m][n], 0, 0, 0);
            }
    }

#pragma unroll
    for (int m = 0; m < 4; ++m)
#pragma unroll
        for (int n = 0; n < 2; ++n)
#pragma unroll
            for (int j = 0; j < 4; ++j) {
                int r = wr * 64 + m * 16 + (lane >> 4) * 4 + j;
                int gi = ts + r;
                if (gi < cnt) {
                    int ci = it * 64 + wc * 32 + n * 16 + (lane & 15);
                    float g = accg[m][n][j], u = accu[m][n][j];
                    float h = g / (1.f + expf(-g)) * u;   // silu(g)*u
                    h_out[(size_t)(base + gi) * IM + ci] = f2bf(h);
                }
            }
}

// ---------------------------------------------------------------- down proj
template<bool SHARED>
__global__ __launch_bounds__(256) void down_kernel(
    const unsigned short* __restrict__ h_in,
    const float* __restrict__ dnp, const float* __restrict__ sdw,
    const int* __restrict__ counts, const int* __restrict__ offsets,
    const int* __restrict__ tok_list, const float* __restrict__ w_list,
    float* __restrict__ out)
{
    const int NCT = HIDN / 128;
    const int NTT = NTOK / 128;
    int bid = blockIdx.x;
    int e, ct, tt;
    if (SHARED) { e = 0; ct = bid / NTT; tt = bid % NTT; }
    else { e = bid / (NCT * NTT); int r = bid % (NCT * NTT); ct = r / NTT; tt = r % NTT; }
    const int cnt = SHARED ? NTOK : counts[e];
    const int ts = tt * 128;
    if (ts >= cnt) return;
    const int base = SHARED ? 0 : offsets[e];
    const float* Bp = SHARED ? (sdw + (size_t)ct * 128 * IM)
                             : (dnp + (size_t)e * HIDN * IM + (size_t)ct * 128 * IM);

    __shared__ unsigned short As[128][32];
    __shared__ unsigned short Bs[128][32];

    const int tid = threadIdx.x;
    const int lane = tid & 63, wid = tid >> 6;
    const int wr = wid >> 1, wc = wid & 1;

    const int TOTROW = SHARED ? NTOK : (NTOK * TOPK);
    size_t arow[2];
#pragma unroll
    for (int p = 0; p < 2; ++p) {
        int r = p * 64 + (tid >> 2);
        int gi = base + ts + r;
        if (gi > TOTROW - 1) gi = TOTROW - 1;
        arow[p] = (size_t)gi * IM + (size_t)((tid & 3) * 8);
    }

    f32x4_t acc[4][4] = {};

    for (int k0 = 0; k0 < IM; k0 += 32) {
        uint4 av[2];
#pragma unroll
        for (int p = 0; p < 2; ++p)
            av[p] = *reinterpret_cast<const uint4*>(h_in + arow[p] + k0);
        ushort4 bv[4];
#pragma unroll
        for (int q = 0; q < 4; ++q) {
            int rr = q * 32 + (tid >> 3);
            float4 f = *reinterpret_cast<const float4*>(Bp + (size_t)rr * IM + k0 + (tid & 7) * 4);
            ushort4 b;
            b.x = f2bf(f.x); b.y = f2bf(f.y); b.z = f2bf(f.z); b.w = f2bf(f.w);
            bv[q] = b;
        }
        __syncthreads();
#pragma unroll
        for (int p = 0; p < 2; ++p)
            *reinterpret_cast<uint4*>(&As[p * 64 + (tid >> 2)][(tid & 3) * 8]) = av[p];
#pragma unroll
        for (int q = 0; q < 4; ++q)
            *reinterpret_cast<ushort4*>(&Bs[q * 32 + (tid >> 3)][(tid & 7) * 4]) = bv[q];
        __syncthreads();

        bf16x8_t a[4], b[4];
#pragma unroll
        for (int m = 0; m < 4; ++m)
            a[m] = *reinterpret_cast<const bf16x8_t*>(&As[wr * 64 + m * 16 + (lane & 15)][(lane >> 4) * 8]);
#pragma unroll
        for (int n = 0; n < 4; ++n)
            b[n] = *reinterpret_cast<const bf16x8_t*>(&Bs[wc * 64 + n * 16 + (lane & 15)][(lane >> 4) * 8]);
#pragma unroll
        for (int m = 0; m < 4; ++m)
#pragma unroll
            for (int n = 0; n < 4; ++n)
                acc[m][n] = __builtin_amdgcn_mfma_f32_16x16x32_bf16(a[m], b[n], acc[m][n], 0, 0, 0);
    }

#pragma unroll
    for (int m = 0; m < 4; ++m)
#pragma unroll
        for (int n = 0; n < 4; ++n)
#pragma unroll
            for (int j = 0; j < 4; ++j) {
                int r = wr * 64 + m * 16 + (lane >> 4) * 4 + j;
                int gi = ts + r;
                int col = ct * 128 + wc * 64 + n * 16 + (lane & 15);
                if (SHARED) {
                    out[(size_t)gi * HIDN + col] = acc[m][n][j];
                } else if (gi < cnt) {
                    int tkn = tok_list[e * NTOK + gi];
                    float wv = w_list[e * NTOK + gi];
                    atomicAdd(&out[(size_t)tkn * HIDN + col], wv * acc[m][n][j]);
                }
            }
}

// ---------------------------------------------------------------- launch
extern "C" void kernel_launch(void* const* d_in, const int* in_sizes, int n_in,
                              void* d_out, int out_size, void* d_ws, size_t ws_size,
                              hipStream_t stream)
{
    (void)in_sizes; (void)n_in; (void)out_size; (void)ws_size;
    const float* x    = (const float*)d_in[0];
    const float* rw   = (const float*)d_in[1];
    const float* bias = (const float*)d_in[2];
    const float* gup  = (const float*)d_in[3];
    const float* dnp  = (const float*)d_in[4];
    const float* sgw  = (const float*)d_in[5];
    const float* suw  = (const float*)d_in[6];
    const float* sdw  = (const float*)d_in[7];
    float* out = (float*)d_out;

    char* w = (char*)d_ws;
    unsigned short* x_bf   = (unsigned short*)w; w += (size_t)NTOK * HIDN * 2;
    unsigned short* h_buf  = (unsigned short*)w; w += (size_t)NTOK * TOPK * IM * 2;
    unsigned short* h_sh   = (unsigned short*)w; w += (size_t)NTOK * IM * 2;
    int*   tok_list = (int*)w;   w += (size_t)NE * NTOK * 4;
    float* w_list   = (float*)w; w += (size_t)NE * NTOK * 4;
    int*   counts   = (int*)w;   w += 128;
    int*   offsets  = (int*)w;   w += 128;

    zero_counts_kernel<<<1, 64, 0, stream>>>(counts);
    router_kernel<<<NTOK, 256, 0, stream>>>(x, rw, bias, x_bf, counts, tok_list, w_list);
    prefix_kernel<<<1, 64, 0, stream>>>(counts, offsets);
    gateup_kernel<false><<<NE * (IM / 64) * (NTOK / 128), 256, 0, stream>>>(
        x_bf, gup, sgw, suw, counts, offsets, tok_list, h_buf);
    gateup_kernel<true><<<(IM / 64) * (NTOK / 128), 256, 0, stream>>>(
        x_bf, gup, sgw, suw, counts, offsets, tok_list, h_sh);
    // shared down writes `out` (assignment) FIRST; routed down atomically adds on top.
    down_kernel<true><<<(HIDN / 128) * (NTOK / 128), 256, 0, stream>>>(
        h_sh, dnp, sdw, counts, offsets, tok_list, w_list, out);
    down_kernel<false><<<NE * (HIDN / 128) * (NTOK / 128), 256, 0, stream>>>(
        h_buf, dnp, sdw, counts, offsets, tok_list, w_list, out);
}

// Round 9
// 1126.935 us; speedup vs baseline: 2.0277x; 2.0277x over previous
//
#include <hip/hip_runtime.h>
#include <cstdint>
#include <cstddef>

#define NTOK  2048
#define HIDN  2048
#define IM    768
#define NE    32
#define TOPK  8
#define NGRP  8
#define GSZ   4
#define TKG   4

typedef __attribute__((ext_vector_type(8))) short bf16x8_t;
typedef __attribute__((ext_vector_type(4))) float f32x4_t;

__device__ __forceinline__ unsigned short f2bf(float f) {
    union { float f; unsigned u; } v; v.f = f;
    unsigned r = v.u + 0x7FFFu + ((v.u >> 16) & 1u);
    return (unsigned short)(r >> 16);
}
__device__ __forceinline__ unsigned pk2bf(float a, float b) {
    return (unsigned)f2bf(a) | ((unsigned)f2bf(b) << 16);
}

// ---------------------------------------------------------------- router (validated r8: eps-band-high)
__global__ __launch_bounds__(256) void router_kernel(
    const float* __restrict__ x, const float* __restrict__ rw,
    const float* __restrict__ bias, unsigned short* __restrict__ x_bf,
    int* __restrict__ counts, int* __restrict__ tok_list, float* __restrict__ w_list)
{
    __shared__ float xs[HIDN];
    __shared__ double part[256];
    __shared__ double lg[NE];
    const int t = blockIdx.x, tid = threadIdx.x;

#pragma unroll
    for (int p = 0; p < 2; ++p) {
        int i = (p * 256 + tid) * 4;
        float4 v = *reinterpret_cast<const float4*>(x + (size_t)t * HIDN + i);
        *reinterpret_cast<float4*>(&xs[i]) = v;
        ushort4 b;
        b.x = f2bf(v.x); b.y = f2bf(v.y); b.z = f2bf(v.z); b.w = f2bf(v.w);
        *reinterpret_cast<ushort4*>(x_bf + (size_t)t * HIDN + i) = b;
    }
    __syncthreads();
    {
        int e = tid >> 3, l8 = tid & 7;
        const float* wrow = rw + (size_t)e * HIDN;
        double acc = 0.0;
        for (int k = l8 * 4; k < HIDN; k += 32) {
            float4 v = *reinterpret_cast<const float4*>(wrow + k);
            acc += (double)v.x * (double)xs[k]     + (double)v.y * (double)xs[k + 1]
                 + (double)v.z * (double)xs[k + 2] + (double)v.w * (double)xs[k + 3];
        }
        part[tid] = acc;
    }
    __syncthreads();
    if ((tid & 7) == 0) {
        int e = tid >> 3;
        double s = 0.0;
        for (int i = 0; i < 8; ++i) s += part[e * 8 + i];
        lg[e] = s;
    }
    __syncthreads();
    if (tid == 0) {
        const float EPS = 3e-7f;
        float s32[NE], sfc[NE], gs[NGRP];
        for (int e = 0; e < NE; ++e) {
            s32[e] = (float)(1.0 / (1.0 + exp(-lg[e])));
            sfc[e] = s32[e] + bias[e];
        }
        for (int g = 0; g < NGRP; ++g) {
            float m1 = -1e30f, m2 = -1e30f;
            for (int i = 0; i < GSZ; ++i) {
                float v = sfc[g * GSZ + i];
                if (v > m1) { m2 = m1; m1 = v; }
                else if (v > m2) m2 = v;
            }
            gs[g] = m1 + m2;
        }
        unsigned gmask = 0;
        for (int it = 0; it < TKG; ++it) {
            float best = -1e30f;
            for (int g = 0; g < NGRP; ++g)
                if (!((gmask >> g) & 1u) && gs[g] > best) best = gs[g];
            int bg = 0;
            for (int g = 0; g < NGRP; ++g)
                if (!((gmask >> g) & 1u) && gs[g] >= best - EPS) bg = g;
            gmask |= 1u << bg;
        }
        unsigned emask = 0;
        int idxs[TOPK]; float wv[TOPK];
        float wsum = 0.f;
        for (int j = 0; j < TOPK; ++j) {
            float best = -1e30f;
            for (int e = 0; e < NE; ++e)
                if (((gmask >> (e >> 2)) & 1u) && !((emask >> e) & 1u) && sfc[e] > best)
                    best = sfc[e];
            int be = 0;
            for (int e = 0; e < NE; ++e)
                if (((gmask >> (e >> 2)) & 1u) && !((emask >> e) & 1u) && sfc[e] >= best - EPS)
                    be = e;
            emask |= 1u << be;
            idxs[j] = be;
            wv[j] = s32[be];
            wsum += s32[be];
        }
        float den = wsum + 1e-20f;
        for (int j = 0; j < TOPK; ++j) {
            int e = idxs[j];
            int pos = atomicAdd(&counts[e], 1);
            tok_list[e * NTOK + pos] = t;
            w_list[e * NTOK + pos] = (wv[j] / den) * 2.5f;
        }
    }
}

__global__ void zero_counts_kernel(int* __restrict__ counts) {
    if (threadIdx.x < NE && blockIdx.x == 0) counts[threadIdx.x] = 0;
}

__global__ void prefix_kernel(const int* __restrict__ counts, int* __restrict__ offsets) {
    if (threadIdx.x == 0 && blockIdx.x == 0) {
        int a = 0;
        for (int e = 0; e < NE; ++e) { offsets[e] = a; a += counts[e]; }
    }
}

// ---------------------------------------------------------------- gate_up (+SiLU fused)
// 128x128 tile, BK=64, double-buffered swizzled LDS, reg-staged async loads.
template<bool SHARED>
__global__ __launch_bounds__(256) void gateup_kernel(
    const unsigned short* __restrict__ x_bf,
    const float* __restrict__ gup,
    const float* __restrict__ sgw, const float* __restrict__ suw,
    const int* __restrict__ counts, const int* __restrict__ offsets,
    const int* __restrict__ tok_list,
    unsigned short* __restrict__ h_out)
{
    const int NTT = NTOK / 128;   // 16
    int e, it, tt;
    if (SHARED) { e = 0; it = blockIdx.x / NTT; tt = blockIdx.x % NTT; }
    else {
        // XCD-bijective swizzle: grid 6144 = 8 * 768; consecutive logical ids
        // (same expert, same i-tile, successive token tiles) share an XCD L2.
        int logical = (blockIdx.x & 7) * 768 + (blockIdx.x >> 3);
        e = logical / 192; int r = logical % 192; it = r / NTT; tt = r % NTT;
    }
    const int cnt = SHARED ? NTOK : counts[e];
    const int ts = tt * 128;
    if (ts >= cnt) return;
    const int base = SHARED ? 0 : offsets[e];
    const float* Bg = SHARED ? (sgw + (size_t)it * 64 * HIDN)
                             : (gup + (size_t)e * (2 * IM) * HIDN + (size_t)it * 64 * HIDN);
    const float* Bu = SHARED ? (suw + (size_t)it * 64 * HIDN)
                             : (gup + (size_t)e * (2 * IM) * HIDN + (size_t)(IM + it * 64) * HIDN);

    __shared__ unsigned short As[2][128 * 64];   // 32 KB
    __shared__ unsigned short Bs[2][128 * 64];   // 32 KB

    const int tid = threadIdx.x;
    const int lane = tid & 63, wid = tid >> 6;
    const int wr = wid >> 1, wc = wid & 1;
    const int lr = lane & 15, lk = lane >> 4;

    // staging: thread -> (row, 32-elem half)
    const int ra = tid >> 1, ha = tid & 1;
    int gi_a = ts + ra;
    int tok;
    if (SHARED) tok = (gi_a < NTOK) ? gi_a : 0;
    else        tok = (gi_a < cnt) ? tok_list[e * NTOK + gi_a] : 0;
    const unsigned short* aptr = x_bf + (size_t)tok * HIDN + ha * 32;
    const float* bptr = ((ra < 64) ? (Bg + (size_t)ra * HIDN) : (Bu + (size_t)(ra - 64) * HIDN)) + ha * 32;
    const int swz = (ra & 7) << 4;

    uint4 av[4]; float4 bv[8];
    auto GLOAD = [&](int K0) {
#pragma unroll
        for (int c = 0; c < 4; ++c) av[c] = *reinterpret_cast<const uint4*>(aptr + K0 + c * 8);
#pragma unroll
        for (int c = 0; c < 8; ++c) bv[c] = *reinterpret_cast<const float4*>(bptr + K0 + c * 4);
    };

    f32x4_t accg[4][2] = {};
    f32x4_t accu[4][2] = {};

    GLOAD(0);
    const int NK = HIDN / 64;   // 32
    for (int t = 0; t < NK; ++t) {
        const int buf = t & 1;
        uint4 bw[4];
#pragma unroll
        for (int c = 0; c < 4; ++c) {
            bw[c].x = pk2bf(bv[2 * c].x, bv[2 * c].y);
            bw[c].y = pk2bf(bv[2 * c].z, bv[2 * c].w);
            bw[c].z = pk2bf(bv[2 * c + 1].x, bv[2 * c + 1].y);
            bw[c].w = pk2bf(bv[2 * c + 1].z, bv[2 * c + 1].w);
        }
        __syncthreads();   // prior reads of this buf are complete
        {
            char* ab = (char*)&As[buf][ra * 64];
            char* bb = (char*)&Bs[buf][ra * 64];
#pragma unroll
            for (int c = 0; c < 4; ++c) {
                *reinterpret_cast<uint4*>(ab + ((ha * 64 + c * 16) ^ swz)) = av[c];
                *reinterpret_cast<uint4*>(bb + ((ha * 64 + c * 16) ^ swz)) = bw[c];
            }
        }
        if (t + 1 < NK) GLOAD((t + 1) * 64);   // async: latency hides under MFMA phase
        __syncthreads();   // writes visible

        const char* Ab = (const char*)&As[buf][0];
        const char* Bb = (const char*)&Bs[buf][0];
#pragma unroll
        for (int ks = 0; ks < 2; ++ks) {
            const int kb = ks * 64 + lk * 16;
            bf16x8_t a[4], bg[2], bu[2];
#pragma unroll
            for (int m = 0; m < 4; ++m) {
                int rr = wr * 64 + m * 16 + lr;
                a[m] = *reinterpret_cast<const bf16x8_t*>(Ab + rr * 128 + (kb ^ ((rr & 7) << 4)));
            }
#pragma unroll
            for (int n = 0; n < 2; ++n) {
                int rg = wc * 32 + n * 16 + lr;
                int ru = 64 + wc * 32 + n * 16 + lr;
                bg[n] = *reinterpret_cast<const bf16x8_t*>(Bb + rg * 128 + (kb ^ ((rg & 7) << 4)));
                bu[n] = *reinterpret_cast<const bf16x8_t*>(Bb + ru * 128 + (kb ^ ((ru & 7) << 4)));
            }
#pragma unroll
            for (int m = 0; m < 4; ++m)
#pragma unroll
                for (int n = 0; n < 2; ++n) {
                    accg[m][n] = __builtin_amdgcn_mfma_f32_16x16x32_bf16(a[m], bg[n], accg[m][n], 0, 0, 0);
                    accu[m][n] = __builtin_amdgcn_mfma_f32_16x16x32_bf16(a[m], bu[n], accu[m][n], 0, 0, 0);
                }
        }
    }

#pragma unroll
    for (int m = 0; m < 4; ++m)
#pragma unroll
        for (int n = 0; n < 2; ++n)
#pragma unroll
            for (int j = 0; j < 4; ++j) {
                int r = wr * 64 + m * 16 + (lane >> 4) * 4 + j;
                int gi = ts + r;
                if (gi < cnt) {
                    int ci = it * 64 + wc * 32 + n * 16 + (lane & 15);
                    float g = accg[m][n][j], u = accu[m][n][j];
                    float h = g / (1.f + expf(-g)) * u;   // silu(g)*u
                    h_out[(size_t)(base + gi) * IM + ci] = f2bf(h);
                }
            }
}

// ---------------------------------------------------------------- down proj
template<bool SHARED>
__global__ __launch_bounds__(256) void down_kernel(
    const unsigned short* __restrict__ h_in,
    const float* __restrict__ dnp, const float* __restrict__ sdw,
    const int* __restrict__ counts, const int* __restrict__ offsets,
    const int* __restrict__ tok_list, const float* __restrict__ w_list,
    float* __restrict__ out)
{
    const int NTT = NTOK / 128;   // 16
    int e, ct, tt;
    if (SHARED) { e = 0; ct = blockIdx.x / NTT; tt = blockIdx.x % NTT; }
    else {
        // grid 8192 = 8 * 1024
        int logical = (blockIdx.x & 7) * 1024 + (blockIdx.x >> 3);
        e = logical / 256; int r = logical % 256; ct = r / NTT; tt = r % NTT;
    }
    const int cnt = SHARED ? NTOK : counts[e];
    const int ts = tt * 128;
    if (ts >= cnt) return;
    const int base = SHARED ? 0 : offsets[e];
    const float* Bp = SHARED ? (sdw + (size_t)ct * 128 * IM)
                             : (dnp + (size_t)e * HIDN * IM + (size_t)ct * 128 * IM);

    __shared__ unsigned short As[2][128 * 64];
    __shared__ unsigned short Bs[2][128 * 64];

    const int tid = threadIdx.x;
    const int lane = tid & 63, wid = tid >> 6;
    const int wr = wid >> 1, wc = wid & 1;
    const int lr = lane & 15, lk = lane >> 4;

    const int TOTROW = SHARED ? NTOK : (NTOK * TOPK);
    const int ra = tid >> 1, ha = tid & 1;
    int gi_a = base + ts + ra;
    if (gi_a > TOTROW - 1) gi_a = TOTROW - 1;
    const unsigned short* aptr = h_in + (size_t)gi_a * IM + ha * 32;
    const float* bptr = Bp + (size_t)ra * IM + ha * 32;
    const int swz = (ra & 7) << 4;

    uint4 av[4]; float4 bv[8];
    auto GLOAD = [&](int K0) {
#pragma unroll
        for (int c = 0; c < 4; ++c) av[c] = *reinterpret_cast<const uint4*>(aptr + K0 + c * 8);
#pragma unroll
        for (int c = 0; c < 8; ++c) bv[c] = *reinterpret_cast<const float4*>(bptr + K0 + c * 4);
    };

    f32x4_t acc[4][4] = {};

    GLOAD(0);
    const int NK = IM / 64;   // 12
    for (int t = 0; t < NK; ++t) {
        const int buf = t & 1;
        uint4 bw[4];
#pragma unroll
        for (int c = 0; c < 4; ++c) {
            bw[c].x = pk2bf(bv[2 * c].x, bv[2 * c].y);
            bw[c].y = pk2bf(bv[2 * c].z, bv[2 * c].w);
            bw[c].z = pk2bf(bv[2 * c + 1].x, bv[2 * c + 1].y);
            bw[c].w = pk2bf(bv[2 * c + 1].z, bv[2 * c + 1].w);
        }
        __syncthreads();
        {
            char* ab = (char*)&As[buf][ra * 64];
            char* bb = (char*)&Bs[buf][ra * 64];
#pragma unroll
            for (int c = 0; c < 4; ++c) {
                *reinterpret_cast<uint4*>(ab + ((ha * 64 + c * 16) ^ swz)) = av[c];
                *reinterpret_cast<uint4*>(bb + ((ha * 64 + c * 16) ^ swz)) = bw[c];
            }
        }
        if (t + 1 < NK) GLOAD((t + 1) * 64);
        __syncthreads();

        const char* Ab = (const char*)&As[buf][0];
        const char* Bb = (const char*)&Bs[buf][0];
#pragma unroll
        for (int ks = 0; ks < 2; ++ks) {
            const int kb = ks * 64 + lk * 16;
            bf16x8_t a[4], b[4];
#pragma unroll
            for (int m = 0; m < 4; ++m) {
                int rr = wr * 64 + m * 16 + lr;
                a[m] = *reinterpret_cast<const bf16x8_t*>(Ab + rr * 128 + (kb ^ ((rr & 7) << 4)));
            }
#pragma unroll
            for (int n = 0; n < 4; ++n) {
                int rc = wc * 64 + n * 16 + lr;
                b[n] = *reinterpret_cast<const bf16x8_t*>(Bb + rc * 128 + (kb ^ ((rc & 7) << 4)));
            }
#pragma unroll
            for (int m = 0; m < 4; ++m)
#pragma unroll
                for (int n = 0; n < 4; ++n)
                    acc[m][n] = __builtin_amdgcn_mfma_f32_16x16x32_bf16(a[m], b[n], acc[m][n], 0, 0, 0);
        }
    }

#pragma unroll
    for (int m = 0; m < 4; ++m)
#pragma unroll
        for (int n = 0; n < 4; ++n)
#pragma unroll
            for (int j = 0; j < 4; ++j) {
                int r = wr * 64 + m * 16 + (lane >> 4) * 4 + j;
                int gi = ts + r;
                int col = ct * 128 + wc * 64 + n * 16 + (lane & 15);
                if (SHARED) {
                    out[(size_t)gi * HIDN + col] = acc[m][n][j];
                } else if (gi < cnt) {
                    int tkn = tok_list[e * NTOK + gi];
                    float wv = w_list[e * NTOK + gi];
                    atomicAdd(&out[(size_t)tkn * HIDN + col], wv * acc[m][n][j]);
                }
            }
}

// ---------------------------------------------------------------- launch
extern "C" void kernel_launch(void* const* d_in, const int* in_sizes, int n_in,
                              void* d_out, int out_size, void* d_ws, size_t ws_size,
                              hipStream_t stream)
{
    (void)in_sizes; (void)n_in; (void)out_size; (void)ws_size;
    const float* x    = (const float*)d_in[0];
    const float* rw   = (const float*)d_in[1];
    const float* bias = (const float*)d_in[2];
    const float* gup  = (const float*)d_in[3];
    const float* dnp  = (const float*)d_in[4];
    const float* sgw  = (const float*)d_in[5];
    const float* suw  = (const float*)d_in[6];
    const float* sdw  = (const float*)d_in[7];
    float* out = (float*)d_out;

    char* w = (char*)d_ws;
    unsigned short* x_bf   = (unsigned short*)w; w += (size_t)NTOK * HIDN * 2;
    unsigned short* h_buf  = (unsigned short*)w; w += (size_t)NTOK * TOPK * IM * 2;
    unsigned short* h_sh   = (unsigned short*)w; w += (size_t)NTOK * IM * 2;
    int*   tok_list = (int*)w;   w += (size_t)NE * NTOK * 4;
    float* w_list   = (float*)w; w += (size_t)NE * NTOK * 4;
    int*   counts   = (int*)w;   w += 128;
    int*   offsets  = (int*)w;   w += 128;

    zero_counts_kernel<<<1, 64, 0, stream>>>(counts);
    router_kernel<<<NTOK, 256, 0, stream>>>(x, rw, bias, x_bf, counts, tok_list, w_list);
    prefix_kernel<<<1, 64, 0, stream>>>(counts, offsets);
    gateup_kernel<false><<<NE * (IM / 64) * (NTOK / 128), 256, 0, stream>>>(
        x_bf, gup, sgw, suw, counts, offsets, tok_list, h_buf);
    gateup_kernel<true><<<(IM / 64) * (NTOK / 128), 256, 0, stream>>>(
        x_bf, gup, sgw, suw, counts, offsets, tok_list, h_sh);
    // shared down writes `out` (assignment) FIRST; routed down atomically adds on top.
    down_kernel<true><<<(HIDN / 128) * (NTOK / 128), 256, 0, stream>>>(
        h_sh, dnp, sdw, counts, offsets, tok_list, w_list, out);
    down_kernel<false><<<NE * (HIDN / 128) * (NTOK / 128), 256, 0, stream>>>(
        h_buf, dnp, sdw, counts, offsets, tok_list, w_list, out);
}

// Round 10
// 829.547 us; speedup vs baseline: 2.7546x; 1.3585x over previous
//
#include <hip/hip_runtime.h>
#include <cstdint>
#include <cstddef>

#define NTOK  2048
#define HIDN  2048
#define IM    768
#define NE    32
#define TOPK  8
#define NGRP  8
#define GSZ   4
#define TKG   4

typedef __attribute__((ext_vector_type(8))) short bf16x8_t;
typedef __attribute__((ext_vector_type(4))) float f32x4_t;

__device__ __forceinline__ unsigned short f2bf(float f) {
    union { float f; unsigned u; } v; v.f = f;
    unsigned r = v.u + 0x7FFFu + ((v.u >> 16) & 1u);
    return (unsigned short)(r >> 16);
}
__device__ __forceinline__ unsigned pk2bf(float a, float b) {
    return (unsigned)f2bf(a) | ((unsigned)f2bf(b) << 16);
}

__device__ __forceinline__ void gload16(const void* gptr, void* lptr) {
    __builtin_amdgcn_global_load_lds(
        (const __attribute__((address_space(1))) unsigned int*)gptr,
        (__attribute__((address_space(3))) unsigned int*)lptr,
        16, 0, 0);
}

// ---------------------------------------------------------------- router (validated r8)
__global__ __launch_bounds__(256) void router_kernel(
    const float* __restrict__ x, const float* __restrict__ rw,
    const float* __restrict__ bias, unsigned short* __restrict__ x_bf,
    int* __restrict__ counts, int* __restrict__ tok_list, float* __restrict__ w_list)
{
    __shared__ float xs[HIDN];
    __shared__ double part[256];
    __shared__ double lg[NE];
    const int t = blockIdx.x, tid = threadIdx.x;

#pragma unroll
    for (int p = 0; p < 2; ++p) {
        int i = (p * 256 + tid) * 4;
        float4 v = *reinterpret_cast<const float4*>(x + (size_t)t * HIDN + i);
        *reinterpret_cast<float4*>(&xs[i]) = v;
        ushort4 b;
        b.x = f2bf(v.x); b.y = f2bf(v.y); b.z = f2bf(v.z); b.w = f2bf(v.w);
        *reinterpret_cast<ushort4*>(x_bf + (size_t)t * HIDN + i) = b;
    }
    __syncthreads();
    {
        int e = tid >> 3, l8 = tid & 7;
        const float* wrow = rw + (size_t)e * HIDN;
        double acc = 0.0;
        for (int k = l8 * 4; k < HIDN; k += 32) {
            float4 v = *reinterpret_cast<const float4*>(wrow + k);
            acc += (double)v.x * (double)xs[k]     + (double)v.y * (double)xs[k + 1]
                 + (double)v.z * (double)xs[k + 2] + (double)v.w * (double)xs[k + 3];
        }
        part[tid] = acc;
    }
    __syncthreads();
    if ((tid & 7) == 0) {
        int e = tid >> 3;
        double s = 0.0;
        for (int i = 0; i < 8; ++i) s += part[e * 8 + i];
        lg[e] = s;
    }
    __syncthreads();
    if (tid == 0) {
        const float EPS = 3e-7f;
        float s32[NE], sfc[NE], gs[NGRP];
        for (int e = 0; e < NE; ++e) {
            s32[e] = (float)(1.0 / (1.0 + exp(-lg[e])));
            sfc[e] = s32[e] + bias[e];
        }
        for (int g = 0; g < NGRP; ++g) {
            float m1 = -1e30f, m2 = -1e30f;
            for (int i = 0; i < GSZ; ++i) {
                float v = sfc[g * GSZ + i];
                if (v > m1) { m2 = m1; m1 = v; }
                else if (v > m2) m2 = v;
            }
            gs[g] = m1 + m2;
        }
        unsigned gmask = 0;
        for (int it = 0; it < TKG; ++it) {
            float best = -1e30f;
            for (int g = 0; g < NGRP; ++g)
                if (!((gmask >> g) & 1u) && gs[g] > best) best = gs[g];
            int bg = 0;
            for (int g = 0; g < NGRP; ++g)
                if (!((gmask >> g) & 1u) && gs[g] >= best - EPS) bg = g;
            gmask |= 1u << bg;
        }
        unsigned emask = 0;
        int idxs[TOPK]; float wv[TOPK];
        float wsum = 0.f;
        for (int j = 0; j < TOPK; ++j) {
            float best = -1e30f;
            for (int e = 0; e < NE; ++e)
                if (((gmask >> (e >> 2)) & 1u) && !((emask >> e) & 1u) && sfc[e] > best)
                    best = sfc[e];
            int be = 0;
            for (int e = 0; e < NE; ++e)
                if (((gmask >> (e >> 2)) & 1u) && !((emask >> e) & 1u) && sfc[e] >= best - EPS)
                    be = e;
            emask |= 1u << be;
            idxs[j] = be;
            wv[j] = s32[be];
            wsum += s32[be];
        }
        float den = wsum + 1e-20f;
        for (int j = 0; j < TOPK; ++j) {
            int e = idxs[j];
            int pos = atomicAdd(&counts[e], 1);
            tok_list[e * NTOK + pos] = t;
            w_list[e * NTOK + pos] = (wv[j] / den) * 2.5f;
        }
    }
}

__global__ void zero_counts_kernel(int* __restrict__ counts) {
    if (threadIdx.x < NE && blockIdx.x == 0) counts[threadIdx.x] = 0;
}

__global__ void prefix_kernel(const int* __restrict__ counts, int* __restrict__ offsets) {
    if (threadIdx.x == 0 && blockIdx.x == 0) {
        int a = 0;
        for (int e = 0; e < NE; ++e) { offsets[e] = a; a += counts[e]; }
    }
}

// ---------------------------------------------------------------- f32 -> bf16 weight convert
__global__ __launch_bounds__(256) void cvt_kernel(
    const float* __restrict__ src, unsigned short* __restrict__ dst, int n8)
{
    int stride = gridDim.x * blockDim.x;
    for (int i = blockIdx.x * blockDim.x + threadIdx.x; i < n8; i += stride) {
        float4 a = *reinterpret_cast<const float4*>(src + (size_t)i * 8);
        float4 b = *reinterpret_cast<const float4*>(src + (size_t)i * 8 + 4);
        uint4 o;
        o.x = pk2bf(a.x, a.y); o.y = pk2bf(a.z, a.w);
        o.z = pk2bf(b.x, b.y); o.w = pk2bf(b.z, b.w);
        *reinterpret_cast<uint4*>(dst + (size_t)i * 8) = o;
    }
}

// ---------------------------------------------------------------- gate_up v2 (bf16 weights, global_load_lds)
// 128x128 tile, BK=64, single-buffered 32KB LDS, linear dest + inverse-swizzled source.
template<bool SHARED>
__global__ __launch_bounds__(256) void gateup_v2(
    const unsigned short* __restrict__ x_bf,
    const unsigned short* __restrict__ gup_bf,
    const unsigned short* __restrict__ sgw_bf, const unsigned short* __restrict__ suw_bf,
    const int* __restrict__ counts, const int* __restrict__ offsets,
    const int* __restrict__ tok_list,
    unsigned short* __restrict__ h_out)
{
    const int NTT = NTOK / 128;   // 16
    int e, it, tt;
    if (SHARED) { e = 0; it = blockIdx.x / NTT; tt = blockIdx.x % NTT; }
    else {
        int logical = (blockIdx.x & 7) * 768 + (blockIdx.x >> 3);   // grid 6144 = 8*768
        e = logical / 192; int r = logical % 192; it = r / NTT; tt = r % NTT;
    }
    const int cnt = SHARED ? NTOK : counts[e];
    const int ts = tt * 128;
    if (ts >= cnt) return;
    const int base = SHARED ? 0 : offsets[e];

    __shared__ unsigned short As[128 * 64];   // 16 KB
    __shared__ unsigned short Bs[128 * 64];   // 16 KB

    const int tid = threadIdx.x;
    const int lane = tid & 63, wid = tid >> 6;
    const int wr = wid >> 1, wc = wid & 1;
    const int lr = lane & 15, lk = lane >> 4;

    // staging: wave wid chunk i covers rows (wid*4+i)*8..+8; lane -> row +(lane>>3), slot lane&7.
    // LDS dest linear (HW: base+lane*16); source slot = slot ^ (row&7)  (involution, rule #21).
    const char* aSrc[4];
    const char* bSrc[4];
    {
        const unsigned short* BgW = SHARED ? (sgw_bf + (size_t)it * 64 * HIDN)
                                           : (gup_bf + (size_t)e * (2 * IM) * HIDN + (size_t)it * 64 * HIDN);
        const unsigned short* BuW = SHARED ? (suw_bf + (size_t)it * 64 * HIDN)
                                           : (gup_bf + (size_t)e * (2 * IM) * HIDN + (size_t)(IM + it * 64) * HIDN);
#pragma unroll
        for (int i = 0; i < 4; ++i) {
            int r = (wid * 4 + i) * 8 + (lane >> 3);
            int soff = (((lane & 7) ^ (r & 7)) << 4);
            int gi = ts + r;
            int tok;
            if (SHARED) tok = (gi < NTOK) ? gi : 0;
            else        tok = (gi < cnt) ? tok_list[e * NTOK + gi] : 0;
            aSrc[i] = (const char*)(x_bf + (size_t)tok * HIDN) + soff;
            const unsigned short* wrow = (r < 64) ? (BgW + (size_t)r * HIDN)
                                                  : (BuW + (size_t)(r - 64) * HIDN);
            bSrc[i] = (const char*)wrow + soff;
        }
    }

    f32x4_t accg[4][2] = {};
    f32x4_t accu[4][2] = {};

    const int NK = HIDN / 64;   // 32
    for (int t = 0; t < NK; ++t) {
        const int kByte = t * 128;
        if (t) __syncthreads();          // prior compute finished reading LDS
#pragma unroll
        for (int i = 0; i < 4; ++i) {
            gload16(aSrc[i] + kByte, (char*)As + (wid * 4 + i) * 1024);
            gload16(bSrc[i] + kByte, (char*)Bs + (wid * 4 + i) * 1024);
        }
        __syncthreads();                 // compiler drains vmcnt(0) before barrier

        const char* Ab = (const char*)As;
        const char* Bb = (const char*)Bs;
#pragma unroll
        for (int ks = 0; ks < 2; ++ks) {
            const int kb = ks * 64 + lk * 16;
            bf16x8_t a[4], bg[2], bu[2];
#pragma unroll
            for (int m = 0; m < 4; ++m) {
                int rr = wr * 64 + m * 16 + lr;
                a[m] = *reinterpret_cast<const bf16x8_t*>(Ab + rr * 128 + (kb ^ ((rr & 7) << 4)));
            }
#pragma unroll
            for (int n = 0; n < 2; ++n) {
                int rg = wc * 32 + n * 16 + lr;
                int ru = 64 + wc * 32 + n * 16 + lr;
                bg[n] = *reinterpret_cast<const bf16x8_t*>(Bb + rg * 128 + (kb ^ ((rg & 7) << 4)));
                bu[n] = *reinterpret_cast<const bf16x8_t*>(Bb + ru * 128 + (kb ^ ((ru & 7) << 4)));
            }
#pragma unroll
            for (int m = 0; m < 4; ++m)
#pragma unroll
                for (int n = 0; n < 2; ++n) {
                    accg[m][n] = __builtin_amdgcn_mfma_f32_16x16x32_bf16(a[m], bg[n], accg[m][n], 0, 0, 0);
                    accu[m][n] = __builtin_amdgcn_mfma_f32_16x16x32_bf16(a[m], bu[n], accu[m][n], 0, 0, 0);
                }
        }
    }

#pragma unroll
    for (int m = 0; m < 4; ++m)
#pragma unroll
        for (int n = 0; n < 2; ++n)
#pragma unroll
            for (int j = 0; j < 4; ++j) {
                int r = wr * 64 + m * 16 + (lane >> 4) * 4 + j;
                int gi = ts + r;
                if (gi < cnt) {
                    int ci = it * 64 + wc * 32 + n * 16 + (lane & 15);
                    float g = accg[m][n][j], u = accu[m][n][j];
                    float h = g / (1.f + expf(-g)) * u;   // silu(g)*u
                    h_out[(size_t)(base + gi) * IM + ci] = f2bf(h);
                }
            }
}

// ---------------------------------------------------------------- down v2 (bf16 weights, global_load_lds)
template<bool SHARED>
__global__ __launch_bounds__(256) void down_v2(
    const unsigned short* __restrict__ h_in,
    const unsigned short* __restrict__ dnp_bf, const unsigned short* __restrict__ sdw_bf,
    const int* __restrict__ counts, const int* __restrict__ offsets,
    const int* __restrict__ tok_list, const float* __restrict__ w_list,
    float* __restrict__ out)
{
    const int NTT = NTOK / 128;   // 16
    int e, ct, tt;
    if (SHARED) { e = 0; ct = blockIdx.x / NTT; tt = blockIdx.x % NTT; }
    else {
        int logical = (blockIdx.x & 7) * 1024 + (blockIdx.x >> 3);   // grid 8192 = 8*1024
        e = logical / 256; int r = logical % 256; ct = r / NTT; tt = r % NTT;
    }
    const int cnt = SHARED ? NTOK : counts[e];
    const int ts = tt * 128;
    if (ts >= cnt) return;
    const int base = SHARED ? 0 : offsets[e];

    __shared__ unsigned short As[128 * 64];
    __shared__ unsigned short Bs[128 * 64];

    const int tid = threadIdx.x;
    const int lane = tid & 63, wid = tid >> 6;
    const int wr = wid >> 1, wc = wid & 1;
    const int lr = lane & 15, lk = lane >> 4;

    const int TOTROW = SHARED ? NTOK : (NTOK * TOPK);
    const char* aSrc[4];
    const char* bSrc[4];
    {
        const unsigned short* Bw = SHARED ? (sdw_bf + (size_t)ct * 128 * IM)
                                          : (dnp_bf + (size_t)e * HIDN * IM + (size_t)ct * 128 * IM);
#pragma unroll
        for (int i = 0; i < 4; ++i) {
            int r = (wid * 4 + i) * 8 + (lane >> 3);
            int soff = (((lane & 7) ^ (r & 7)) << 4);
            int gi = base + ts + r;
            if (gi > TOTROW - 1) gi = TOTROW - 1;
            aSrc[i] = (const char*)(h_in + (size_t)gi * IM) + soff;
            bSrc[i] = (const char*)(Bw + (size_t)r * IM) + soff;
        }
    }

    f32x4_t acc[4][4] = {};

    const int NK = IM / 64;   // 12
    for (int t = 0; t < NK; ++t) {
        const int kByte = t * 128;
        if (t) __syncthreads();
#pragma unroll
        for (int i = 0; i < 4; ++i) {
            gload16(aSrc[i] + kByte, (char*)As + (wid * 4 + i) * 1024);
            gload16(bSrc[i] + kByte, (char*)Bs + (wid * 4 + i) * 1024);
        }
        __syncthreads();

        const char* Ab = (const char*)As;
        const char* Bb = (const char*)Bs;
#pragma unroll
        for (int ks = 0; ks < 2; ++ks) {
            const int kb = ks * 64 + lk * 16;
            bf16x8_t a[4], b[4];
#pragma unroll
            for (int m = 0; m < 4; ++m) {
                int rr = wr * 64 + m * 16 + lr;
                a[m] = *reinterpret_cast<const bf16x8_t*>(Ab + rr * 128 + (kb ^ ((rr & 7) << 4)));
            }
#pragma unroll
            for (int n = 0; n < 4; ++n) {
                int rc = wc * 64 + n * 16 + lr;
                b[n] = *reinterpret_cast<const bf16x8_t*>(Bb + rc * 128 + (kb ^ ((rc & 7) << 4)));
            }
#pragma unroll
            for (int m = 0; m < 4; ++m)
#pragma unroll
                for (int n = 0; n < 4; ++n)
                    acc[m][n] = __builtin_amdgcn_mfma_f32_16x16x32_bf16(a[m], b[n], acc[m][n], 0, 0, 0);
        }
    }

#pragma unroll
    for (int m = 0; m < 4; ++m)
#pragma unroll
        for (int n = 0; n < 4; ++n)
#pragma unroll
            for (int j = 0; j < 4; ++j) {
                int r = wr * 64 + m * 16 + (lane >> 4) * 4 + j;
                int gi = ts + r;
                int col = ct * 128 + wc * 64 + n * 16 + (lane & 15);
                if (SHARED) {
                    out[(size_t)gi * HIDN + col] = acc[m][n][j];
                } else if (gi < cnt) {
                    int tkn = tok_list[e * NTOK + gi];
                    float wv = w_list[e * NTOK + gi];
                    atomicAdd(&out[(size_t)tkn * HIDN + col], wv * acc[m][n][j]);
                }
            }
}

// ---------------------------------------------------------------- fallback (r9) kernels, f32 weights
template<bool SHARED>
__global__ __launch_bounds__(256) void gateup_f32w(
    const unsigned short* __restrict__ x_bf,
    const float* __restrict__ gup,
    const float* __restrict__ sgw, const float* __restrict__ suw,
    const int* __restrict__ counts, const int* __restrict__ offsets,
    const int* __restrict__ tok_list,
    unsigned short* __restrict__ h_out)
{
    const int NTT = NTOK / 128;
    int e, it, tt;
    if (SHARED) { e = 0; it = blockIdx.x / NTT; tt = blockIdx.x % NTT; }
    else {
        int logical = (blockIdx.x & 7) * 768 + (blockIdx.x >> 3);
        e = logical / 192; int r = logical % 192; it = r / NTT; tt = r % NTT;
    }
    const int cnt = SHARED ? NTOK : counts[e];
    const int ts = tt * 128;
    if (ts >= cnt) return;
    const int base = SHARED ? 0 : offsets[e];
    const float* Bg = SHARED ? (sgw + (size_t)it * 64 * HIDN)
                             : (gup + (size_t)e * (2 * IM) * HIDN + (size_t)it * 64 * HIDN);
    const float* Bu = SHARED ? (suw + (size_t)it * 64 * HIDN)
                             : (gup + (size_t)e * (2 * IM) * HIDN + (size_t)(IM + it * 64) * HIDN);

    __shared__ unsigned short As[2][128 * 64];
    __shared__ unsigned short Bs[2][128 * 64];

    const int tid = threadIdx.x;
    const int lane = tid & 63, wid = tid >> 6;
    const int wr = wid >> 1, wc = wid & 1;
    const int lr = lane & 15, lk = lane >> 4;

    const int ra = tid >> 1, ha = tid & 1;
    int gi_a = ts + ra;
    int tok;
    if (SHARED) tok = (gi_a < NTOK) ? gi_a : 0;
    else        tok = (gi_a < cnt) ? tok_list[e * NTOK + gi_a] : 0;
    const unsigned short* aptr = x_bf + (size_t)tok * HIDN + ha * 32;
    const float* bptr = ((ra < 64) ? (Bg + (size_t)ra * HIDN) : (Bu + (size_t)(ra - 64) * HIDN)) + ha * 32;
    const int swz = (ra & 7) << 4;

    uint4 av[4]; float4 bv[8];
    auto GLOAD = [&](int K0) {
#pragma unroll
        for (int c = 0; c < 4; ++c) av[c] = *reinterpret_cast<const uint4*>(aptr + K0 + c * 8);
#pragma unroll
        for (int c = 0; c < 8; ++c) bv[c] = *reinterpret_cast<const float4*>(bptr + K0 + c * 4);
    };

    f32x4_t accg[4][2] = {};
    f32x4_t accu[4][2] = {};

    GLOAD(0);
    const int NK = HIDN / 64;
    for (int t = 0; t < NK; ++t) {
        const int buf = t & 1;
        uint4 bw[4];
#pragma unroll
        for (int c = 0; c < 4; ++c) {
            bw[c].x = pk2bf(bv[2 * c].x, bv[2 * c].y);
            bw[c].y = pk2bf(bv[2 * c].z, bv[2 * c].w);
            bw[c].z = pk2bf(bv[2 * c + 1].x, bv[2 * c + 1].y);
            bw[c].w = pk2bf(bv[2 * c + 1].z, bv[2 * c + 1].w);
        }
        __syncthreads();
        {
            char* ab = (char*)&As[buf][ra * 64];
            char* bb = (char*)&Bs[buf][ra * 64];
#pragma unroll
            for (int c = 0; c < 4; ++c) {
                *reinterpret_cast<uint4*>(ab + ((ha * 64 + c * 16) ^ swz)) = av[c];
                *reinterpret_cast<uint4*>(bb + ((ha * 64 + c * 16) ^ swz)) = bw[c];
            }
        }
        if (t + 1 < NK) GLOAD((t + 1) * 64);
        __syncthreads();

        const char* Ab = (const char*)&As[buf][0];
        const char* Bb = (const char*)&Bs[buf][0];
#pragma unroll
        for (int ks = 0; ks < 2; ++ks) {
            const int kb = ks * 64 + lk * 16;
            bf16x8_t a[4], bg[2], bu[2];
#pragma unroll
            for (int m = 0; m < 4; ++m) {
                int rr = wr * 64 + m * 16 + lr;
                a[m] = *reinterpret_cast<const bf16x8_t*>(Ab + rr * 128 + (kb ^ ((rr & 7) << 4)));
            }
#pragma unroll
            for (int n = 0; n < 2; ++n) {
                int rg = wc * 32 + n * 16 + lr;
                int ru = 64 + wc * 32 + n * 16 + lr;
                bg[n] = *reinterpret_cast<const bf16x8_t*>(Bb + rg * 128 + (kb ^ ((rg & 7) << 4)));
                bu[n] = *reinterpret_cast<const bf16x8_t*>(Bb + ru * 128 + (kb ^ ((ru & 7) << 4)));
            }
#pragma unroll
            for (int m = 0; m < 4; ++m)
#pragma unroll
                for (int n = 0; n < 2; ++n) {
                    accg[m][n] = __builtin_amdgcn_mfma_f32_16x16x32_bf16(a[m], bg[n], accg[m][n], 0, 0, 0);
                    accu[m][n] = __builtin_amdgcn_mfma_f32_16x16x32_bf16(a[m], bu[n], accu[m][n], 0, 0, 0);
                }
        }
    }

#pragma unroll
    for (int m = 0; m < 4; ++m)
#pragma unroll
        for (int n = 0; n < 2; ++n)
#pragma unroll
            for (int j = 0; j < 4; ++j) {
                int r = wr * 64 + m * 16 + (lane >> 4) * 4 + j;
                int gi = ts + r;
                if (gi < cnt) {
                    int ci = it * 64 + wc * 32 + n * 16 + (lane & 15);
                    float g = accg[m][n][j], u = accu[m][n][j];
                    float h = g / (1.f + expf(-g)) * u;
                    h_out[(size_t)(base + gi) * IM + ci] = f2bf(h);
                }
            }
}

template<bool SHARED>
__global__ __launch_bounds__(256) void down_f32w(
    const unsigned short* __restrict__ h_in,
    const float* __restrict__ dnp, const float* __restrict__ sdw,
    const int* __restrict__ counts, const int* __restrict__ offsets,
    const int* __restrict__ tok_list, const float* __restrict__ w_list,
    float* __restrict__ out)
{
    const int NTT = NTOK / 128;
    int e, ct, tt;
    if (SHARED) { e = 0; ct = blockIdx.x / NTT; tt = blockIdx.x % NTT; }
    else {
        int logical = (blockIdx.x & 7) * 1024 + (blockIdx.x >> 3);
        e = logical / 256; int r = logical % 256; ct = r / NTT; tt = r % NTT;
    }
    const int cnt = SHARED ? NTOK : counts[e];
    const int ts = tt * 128;
    if (ts >= cnt) return;
    const int base = SHARED ? 0 : offsets[e];
    const float* Bp = SHARED ? (sdw + (size_t)ct * 128 * IM)
                             : (dnp + (size_t)e * HIDN * IM + (size_t)ct * 128 * IM);

    __shared__ unsigned short As[2][128 * 64];
    __shared__ unsigned short Bs[2][128 * 64];

    const int tid = threadIdx.x;
    const int lane = tid & 63, wid = tid >> 6;
    const int wr = wid >> 1, wc = wid & 1;
    const int lr = lane & 15, lk = lane >> 4;

    const int TOTROW = SHARED ? NTOK : (NTOK * TOPK);
    const int ra = tid >> 1, ha = tid & 1;
    int gi_a = base + ts + ra;
    if (gi_a > TOTROW - 1) gi_a = TOTROW - 1;
    const unsigned short* aptr = h_in + (size_t)gi_a * IM + ha * 32;
    const float* bptr = Bp + (size_t)ra * IM + ha * 32;
    const int swz = (ra & 7) << 4;

    uint4 av[4]; float4 bv[8];
    auto GLOAD = [&](int K0) {
#pragma unroll
        for (int c = 0; c < 4; ++c) av[c] = *reinterpret_cast<const uint4*>(aptr + K0 + c * 8);
#pragma unroll
        for (int c = 0; c < 8; ++c) bv[c] = *reinterpret_cast<const float4*>(bptr + K0 + c * 4);
    };

    f32x4_t acc[4][4] = {};

    GLOAD(0);
    const int NK = IM / 64;
    for (int t = 0; t < NK; ++t) {
        const int buf = t & 1;
        uint4 bw[4];
#pragma unroll
        for (int c = 0; c < 4; ++c) {
            bw[c].x = pk2bf(bv[2 * c].x, bv[2 * c].y);
            bw[c].y = pk2bf(bv[2 * c].z, bv[2 * c].w);
            bw[c].z = pk2bf(bv[2 * c + 1].x, bv[2 * c + 1].y);
            bw[c].w = pk2bf(bv[2 * c + 1].z, bv[2 * c + 1].w);
        }
        __syncthreads();
        {
            char* ab = (char*)&As[buf][ra * 64];
            char* bb = (char*)&Bs[buf][ra * 64];
#pragma unroll
            for (int c = 0; c < 4; ++c) {
                *reinterpret_cast<uint4*>(ab + ((ha * 64 + c * 16) ^ swz)) = av[c];
                *reinterpret_cast<uint4*>(bb + ((ha * 64 + c * 16) ^ swz)) = bw[c];
            }
        }
        if (t + 1 < NK) GLOAD((t + 1) * 64);
        __syncthreads();

        const char* Ab = (const char*)&As[buf][0];
        const char* Bb = (const char*)&Bs[buf][0];
#pragma unroll
        for (int ks = 0; ks < 2; ++ks) {
            const int kb = ks * 64 + lk * 16;
            bf16x8_t a[4], b[4];
#pragma unroll
            for (int m = 0; m < 4; ++m) {
                int rr = wr * 64 + m * 16 + lr;
                a[m] = *reinterpret_cast<const bf16x8_t*>(Ab + rr * 128 + (kb ^ ((rr & 7) << 4)));
            }
#pragma unroll
            for (int n = 0; n < 4; ++n) {
                int rc = wc * 64 + n * 16 + lr;
                b[n] = *reinterpret_cast<const bf16x8_t*>(Bb + rc * 128 + (kb ^ ((rc & 7) << 4)));
            }
#pragma unroll
            for (int m = 0; m < 4; ++m)
#pragma unroll
                for (int n = 0; n < 4; ++n)
                    acc[m][n] = __builtin_amdgcn_mfma_f32_16x16x32_bf16(a[m], b[n], acc[m][n], 0, 0, 0);
        }
    }

#pragma unroll
    for (int m = 0; m < 4; ++m)
#pragma unroll
        for (int n = 0; n < 4; ++n)
#pragma unroll
            for (int j = 0; j < 4; ++j) {
                int r = wr * 64 + m * 16 + (lane >> 4) * 4 + j;
                int gi = ts + r;
                int col = ct * 128 + wc * 64 + n * 16 + (lane & 15);
                if (SHARED) {
                    out[(size_t)gi * HIDN + col] = acc[m][n][j];
                } else if (gi < cnt) {
                    int tkn = tok_list[e * NTOK + gi];
                    float wv = w_list[e * NTOK + gi];
                    atomicAdd(&out[(size_t)tkn * HIDN + col], wv * acc[m][n][j]);
                }
            }
}

// ---------------------------------------------------------------- launch
extern "C" void kernel_launch(void* const* d_in, const int* in_sizes, int n_in,
                              void* d_out, int out_size, void* d_ws, size_t ws_size,
                              hipStream_t stream)
{
    (void)in_sizes; (void)n_in; (void)out_size;
    const float* x    = (const float*)d_in[0];
    const float* rw   = (const float*)d_in[1];
    const float* bias = (const float*)d_in[2];
    const float* gup  = (const float*)d_in[3];
    const float* dnp  = (const float*)d_in[4];
    const float* sgw  = (const float*)d_in[5];
    const float* suw  = (const float*)d_in[6];
    const float* sdw  = (const float*)d_in[7];
    float* out = (float*)d_out;

    char* w = (char*)d_ws;
    unsigned short* x_bf   = (unsigned short*)w; w += (size_t)NTOK * HIDN * 2;
    unsigned short* h_buf  = (unsigned short*)w; w += (size_t)NTOK * TOPK * IM * 2;
    unsigned short* h_sh   = (unsigned short*)w; w += (size_t)NTOK * IM * 2;
    int*   tok_list = (int*)w;   w += (size_t)NE * NTOK * 4;
    float* w_list   = (float*)w; w += (size_t)NE * NTOK * 4;
    int*   counts   = (int*)w;   w += 128;
    int*   offsets  = (int*)w;   w += 128;
    unsigned short* gup_bf = (unsigned short*)w; w += (size_t)NE * 2 * IM * HIDN * 2;
    unsigned short* dnp_bf = (unsigned short*)w; w += (size_t)NE * HIDN * IM * 2;
    unsigned short* sgw_bf = (unsigned short*)w; w += (size_t)IM * HIDN * 2;
    unsigned short* suw_bf = (unsigned short*)w; w += (size_t)IM * HIDN * 2;
    unsigned short* sdw_bf = (unsigned short*)w; w += (size_t)HIDN * IM * 2;
    const size_t NEED = (size_t)(w - (char*)d_ws);

    zero_counts_kernel<<<1, 64, 0, stream>>>(counts);
    router_kernel<<<NTOK, 256, 0, stream>>>(x, rw, bias, x_bf, counts, tok_list, w_list);
    prefix_kernel<<<1, 64, 0, stream>>>(counts, offsets);

    if (ws_size >= NEED) {
        cvt_kernel<<<2048, 256, 0, stream>>>(gup, gup_bf, NE * 2 * IM * HIDN / 8);
        cvt_kernel<<<2048, 256, 0, stream>>>(dnp, dnp_bf, NE * HIDN * IM / 8);
        cvt_kernel<<<256, 256, 0, stream>>>(sgw, sgw_bf, IM * HIDN / 8);
        cvt_kernel<<<256, 256, 0, stream>>>(suw, suw_bf, IM * HIDN / 8);
        cvt_kernel<<<256, 256, 0, stream>>>(sdw, sdw_bf, HIDN * IM / 8);

        gateup_v2<false><<<NE * (IM / 64) * (NTOK / 128), 256, 0, stream>>>(
            x_bf, gup_bf, sgw_bf, suw_bf, counts, offsets, tok_list, h_buf);
        gateup_v2<true><<<(IM / 64) * (NTOK / 128), 256, 0, stream>>>(
            x_bf, gup_bf, sgw_bf, suw_bf, counts, offsets, tok_list, h_sh);
        down_v2<true><<<(HIDN / 128) * (NTOK / 128), 256, 0, stream>>>(
            h_sh, dnp_bf, sdw_bf, counts, offsets, tok_list, w_list, out);
        down_v2<false><<<NE * (HIDN / 128) * (NTOK / 128), 256, 0, stream>>>(
            h_buf, dnp_bf, sdw_bf, counts, offsets, tok_list, w_list, out);
    } else {
        gateup_f32w<false><<<NE * (IM / 64) * (NTOK / 128), 256, 0, stream>>>(
            x_bf, gup, sgw, suw, counts, offsets, tok_list, h_buf);
        gateup_f32w<true><<<(IM / 64) * (NTOK / 128), 256, 0, stream>>>(
            x_bf, gup, sgw, suw, counts, offsets, tok_list, h_sh);
        down_f32w<true><<<(HIDN / 128) * (NTOK / 128), 256, 0, stream>>>(
            h_sh, dnp, sdw, counts, offsets, tok_list, w_list, out);
        down_f32w<false><<<NE * (HIDN / 128) * (NTOK / 128), 256, 0, stream>>>(
            h_buf, dnp, sdw, counts, offsets, tok_list, w_list, out);
    }
}